// Round 1
// baseline (2472.058 us; speedup 1.0000x reference)
//
#include <hip/hip_runtime.h>
#include <math.h>

// ---------------------------------------------------------------------------
// SiameseGNN_GIN: GIN(x1) & GIN(x2) -> cdist -> sort-pool(k=50 by last col)
// -> fc1+LN+ReLU -> fc2+LN+ReLU -> fc3+sigmoid
// Key restructure: (x+agg)@W = x@W + A*(x@W)  => aggregate AFTER the linear,
// so conv2's aggregation is 64-wide. CSR (by dst) gather instead of atomics.
// Distance matrix never materialized: scores (col 198) -> top-50 -> 400 rows.
// ---------------------------------------------------------------------------

// ---------------- CSR build ----------------
__global__ __launch_bounds__(256) void hist_kernel(const int* __restrict__ dst, int E,
                                                   int* __restrict__ counts) {
    int e = blockIdx.x * 256 + threadIdx.x;
    if (e < E) atomicAdd(&counts[dst[e]], 1);
}

__global__ __launch_bounds__(256) void chunksum_kernel(const int* __restrict__ in, int total,
                                                       int* __restrict__ bsum) {
    __shared__ int red[256];
    int t = threadIdx.x;
    int base = blockIdx.x * 1024 + t * 4;
    int s = 0;
#pragma unroll
    for (int j = 0; j < 4; ++j) { int i = base + j; if (i < total) s += in[i]; }
    red[t] = s; __syncthreads();
    for (int off = 128; off; off >>= 1) { if (t < off) red[t] += red[t + off]; __syncthreads(); }
    if (t == 0) bsum[blockIdx.x] = red[0];
}

// exclusive scan of 1024-chunks; chunk base from baseArr (or 0). Optionally dup to out2.
__global__ __launch_bounds__(256) void scanchunk_kernel(const int* __restrict__ in, int total,
                                                        const int* __restrict__ baseArr,
                                                        int* __restrict__ out,
                                                        int* __restrict__ out2) {
    __shared__ int tsum[256];
    int t = threadIdx.x;
    int base_i = blockIdx.x * 1024 + t * 4;
    int v[4];
#pragma unroll
    for (int j = 0; j < 4; ++j) v[j] = (base_i + j < total) ? in[base_i + j] : 0;
    int l0 = 0, l1 = v[0], l2 = v[0] + v[1], l3 = l2 + v[2];
    int s = l3 + v[3];
    tsum[t] = s; __syncthreads();
    for (int off = 1; off < 256; off <<= 1) {
        int x = (t >= off) ? tsum[t - off] : 0;
        __syncthreads();
        tsum[t] += x;
        __syncthreads();
    }
    int cb = baseArr ? baseArr[blockIdx.x] : 0;
    int te = cb + tsum[t] - s;
    int outs[4] = { te + l0, te + l1, te + l2, te + l3 };
#pragma unroll
    for (int j = 0; j < 4; ++j) {
        int i = base_i + j;
        if (i < total) { out[i] = outs[j]; if (out2) out2[i] = outs[j]; }
    }
}

__global__ __launch_bounds__(256) void fill_kernel(const int* __restrict__ src,
                                                   const int* __restrict__ dst, int E,
                                                   int* __restrict__ cur, int* __restrict__ csr) {
    int e = blockIdx.x * 256 + threadIdx.x;
    if (e < E) {
        int d = dst[e];
        int p = atomicAdd(&cur[d], 1);
        csr[p] = src[e];
    }
}

// ---------------- fp32 GEMM: Y[N,KO] = relu?(X[N,KI] @ W[KI,KO] + bias?) ----------------
template <int KI, int KO, bool BIAS, bool RELU>
__global__ __launch_bounds__(256) void gemm_kernel(const float* __restrict__ X,
                                                   const float* __restrict__ Wm,
                                                   const float* __restrict__ bias,
                                                   float* __restrict__ Y, int N) {
    constexpr int TPR = KO / 4;       // threads across columns (float4 cols)
    constexpr int RPT = KO / 16;      // rows per thread (8 for KO=128, 4 for KO=64)
    constexpr int XS = 68;            // 64 rows + 4 pad (keeps 16B alignment)
    __shared__ __align__(16) float wl[32 * KO];
    __shared__ __align__(16) float xt[32 * XS];
    const int t = threadIdx.x;
    const int r0 = blockIdx.x * 64;
    const int tx = t % TPR, ty = t / TPR;
    float4 acc[RPT];
#pragma unroll
    for (int r = 0; r < RPT; ++r) acc[r] = make_float4(0.f, 0.f, 0.f, 0.f);

    for (int kb = 0; kb < KI; kb += 32) {
        __syncthreads();
#pragma unroll
        for (int i = t; i < 32 * KO / 4; i += 256)
            ((float4*)wl)[i] = ((const float4*)Wm)[kb * KO / 4 + i];
#pragma unroll
        for (int L = t; L < 512; L += 256) {
            int row = L >> 3, kq = L & 7;
            int gr = r0 + row;
            float4 v = make_float4(0.f, 0.f, 0.f, 0.f);
            if (gr < N) v = *(const float4*)(X + (size_t)gr * KI + kb + kq * 4);
            xt[(kq * 4 + 0) * XS + row] = v.x;
            xt[(kq * 4 + 1) * XS + row] = v.y;
            xt[(kq * 4 + 2) * XS + row] = v.z;
            xt[(kq * 4 + 3) * XS + row] = v.w;
        }
        __syncthreads();
#pragma unroll
        for (int k = 0; k < 32; ++k) {
            float4 wv = ((const float4*)wl)[k * TPR + tx];
            const float4* xp = (const float4*)(xt + k * XS + ty * RPT);
#pragma unroll
            for (int rq = 0; rq < RPT / 4; ++rq) {
                float4 xv = xp[rq];
                acc[rq*4+0].x += xv.x * wv.x; acc[rq*4+0].y += xv.x * wv.y;
                acc[rq*4+0].z += xv.x * wv.z; acc[rq*4+0].w += xv.x * wv.w;
                acc[rq*4+1].x += xv.y * wv.x; acc[rq*4+1].y += xv.y * wv.y;
                acc[rq*4+1].z += xv.y * wv.z; acc[rq*4+1].w += xv.y * wv.w;
                acc[rq*4+2].x += xv.z * wv.x; acc[rq*4+2].y += xv.z * wv.y;
                acc[rq*4+2].z += xv.z * wv.z; acc[rq*4+2].w += xv.z * wv.w;
                acc[rq*4+3].x += xv.w * wv.x; acc[rq*4+3].y += xv.w * wv.y;
                acc[rq*4+3].z += xv.w * wv.z; acc[rq*4+3].w += xv.w * wv.w;
            }
        }
    }
    float4 b4 = make_float4(0.f, 0.f, 0.f, 0.f);
    if (BIAS) b4 = ((const float4*)bias)[tx];
#pragma unroll
    for (int r = 0; r < RPT; ++r) {
        int gr = r0 + ty * RPT + r;
        if (gr < N) {
            float4 o = make_float4(acc[r].x + b4.x, acc[r].y + b4.y,
                                   acc[r].z + b4.z, acc[r].w + b4.w);
            if (RELU) {
                o.x = fmaxf(o.x, 0.f); o.y = fmaxf(o.y, 0.f);
                o.z = fmaxf(o.z, 0.f); o.w = fmaxf(o.w, 0.f);
            }
            *(float4*)(Y + (size_t)gr * KO + tx * 4) = o;
        }
    }
}

// ---------------- aggregation: out[n] = relu(x[n] + sum_{e:dst=n} x[src] + bias) -------
template <int VEC>  // float4s per row: 32 (width 128) or 16 (width 64)
__global__ __launch_bounds__(256) void agg_kernel(const float* __restrict__ x,
                                                  const int* __restrict__ rs,
                                                  const int* __restrict__ csr,
                                                  const float* __restrict__ bias,
                                                  float* __restrict__ out, int N) {
    const int NPB = 256 / VEC;
    const int t = threadIdx.x;
    const int node = blockIdx.x * NPB + t / VEC;
    const int c = t % VEC;
    if (node >= N) return;
    const int W = VEC * 4;
    float4 acc = ((const float4*)(x + (size_t)node * W))[c];
    const int s1 = rs[node + 1];
    for (int k = rs[node]; k < s1; ++k) {
        int src = csr[k];
        float4 v = ((const float4*)(x + (size_t)src * W))[c];
        acc.x += v.x; acc.y += v.y; acc.z += v.z; acc.w += v.w;
    }
    float4 b4 = ((const float4*)bias)[c];
    acc.x = fmaxf(acc.x + b4.x, 0.f);
    acc.y = fmaxf(acc.y + b4.y, 0.f);
    acc.z = fmaxf(acc.z + b4.z, 0.f);
    acc.w = fmaxf(acc.w + b4.w, 0.f);
    ((float4*)(out + (size_t)node * W))[c] = acc;
}

// ---------------- scores: d(out1[n], out2[198]) via cdist formula, fp64 ----------------
__global__ __launch_bounds__(256) void scores_kernel(const float* __restrict__ out1,
                                                     const float* __restrict__ out2,
                                                     double* __restrict__ sc, int N) {
    const int t = threadIdx.x;
    const int node = blockIdx.x * 4 + (t >> 6);
    const int lane = t & 63;
    if (node >= N) return;
    float a = out1[(size_t)node * 64 + lane];
    float bv = out2[198 * 64 + lane];
    double na = (double)a * a;
    double nb = (double)bv * bv;
    double dd = (double)a * bv;
    for (int off = 32; off; off >>= 1) {
        na += __shfl_xor(na, off);
        nb += __shfl_xor(nb, off);
        dd += __shfl_xor(dd, off);
    }
    if (lane == 0) {
        double sq = na + nb - 2.0 * dd;
        sc[node] = (sq > 0.0) ? sqrt(sq) : 0.0;
    }
}

// ---------------- per-graph top-50 (desc value, asc index) -----------------------------
__global__ __launch_bounds__(256) void topk_kernel(double* __restrict__ sc,
                                                   int* __restrict__ topk, int npg) {
    const int g = blockIdx.x, t = threadIdx.x;
    double* s = sc + (size_t)g * npg;
    __shared__ double sv[256];
    __shared__ int si[256];
    for (int r = 0; r < 50; ++r) {
        double best = -1e300; int bi = 0x3fffffff;
        for (int i = t; i < npg; i += 256) {
            double v = s[i];
            if (v > best || (v == best && i < bi)) { best = v; bi = i; }
        }
        sv[t] = best; si[t] = bi; __syncthreads();
        for (int off = 128; off; off >>= 1) {
            if (t < off) {
                if (sv[t + off] > sv[t] || (sv[t + off] == sv[t] && si[t + off] < si[t])) {
                    sv[t] = sv[t + off]; si[t] = si[t + off];
                }
            }
            __syncthreads();
        }
        if (t == 0) { topk[g * 50 + r] = si[0]; s[si[0]] = -1.0; }
        __syncthreads();
    }
}

// ---------------- pooled rows: d(out1[sel], out2[j]) for 400 rows x 199 cols -----------
__global__ __launch_bounds__(256) void pooled_kernel(const float* __restrict__ out1,
                                                     const float* __restrict__ out2,
                                                     const int* __restrict__ topk,
                                                     float* __restrict__ pooled, int npg) {
    const int bk = blockIdx.x;           // 0..399
    const int g = bk / 50, kk = bk % 50;
    __shared__ float arow[64];
    const int t = threadIdx.x;
    const int node = g * npg + topk[g * 50 + kk];
    if (t < 64) arow[t] = out1[(size_t)node * 64 + t];
    __syncthreads();
    if (t < 199) {
        double na = 0.0, nb = 0.0, dd = 0.0;
        for (int k2 = 0; k2 < 64; ++k2) {
            double a = arow[k2];
            double b = out2[t * 64 + k2];
            na += a * a; nb += b * b; dd += a * b;
        }
        double sq = na + nb - 2.0 * dd;
        pooled[(size_t)g * 9950 + kk * 199 + t] = (float)((sq > 0.0) ? sqrt(sq) : 0.0);
    }
}

// ---------------- fc1: z1[b,f] = pooled[b,:] @ fc1_W[:,f] + b, 8-way k-split ----------
__global__ __launch_bounds__(256) void fc1_kernel(const float* __restrict__ pooled,
                                                  const float* __restrict__ W,
                                                  const float* __restrict__ bias,
                                                  float* __restrict__ z1) {
    const int b = blockIdx.x >> 2, fg = blockIdx.x & 3;
    const int t = threadIdx.x;
    const int f = fg * 32 + (t & 31);
    const int ks = t >> 5;
    const float* p = pooled + (size_t)b * 9950;
    double acc = 0.0;
    for (int i = ks; i < 9950; i += 8)
        acc += (double)p[i] * (double)W[(size_t)i * 128 + f];
    __shared__ double red[256];
    red[t] = acc; __syncthreads();
    for (int off = 4; off; off >>= 1) {
        if (ks < off) red[t] += red[t + off * 32];
        __syncthreads();
    }
    if (ks == 0) z1[b * 128 + f] = (float)(red[t] + (double)bias[f]);
}

// ---------------- head: LN+ReLU, fc2, LN+ReLU, fc3, sigmoid ---------------------------
__global__ __launch_bounds__(128) void head_kernel(const float* __restrict__ z1,
                                                   const float* __restrict__ g1,
                                                   const float* __restrict__ be1,
                                                   const float* __restrict__ W2,
                                                   const float* __restrict__ b2,
                                                   const float* __restrict__ g2,
                                                   const float* __restrict__ be2,
                                                   const float* __restrict__ W3,
                                                   const float* __restrict__ b3,
                                                   float* __restrict__ out) {
    const int b = blockIdx.x, t = threadIdx.x;
    __shared__ double red[128];
    __shared__ float shy[128];
    __shared__ float sh2[64];
    float z = z1[b * 128 + t];
    red[t] = z; __syncthreads();
    for (int off = 64; off; off >>= 1) { if (t < off) red[t] += red[t + off]; __syncthreads(); }
    double mu = red[0] / 128.0; __syncthreads();
    double dv = (double)z - mu;
    red[t] = dv * dv; __syncthreads();
    for (int off = 64; off; off >>= 1) { if (t < off) red[t] += red[t + off]; __syncthreads(); }
    double var = red[0] / 128.0; __syncthreads();
    float y = (float)(dv / sqrt(var + 1e-5)) * g1[t] + be1[t];
    shy[t] = fmaxf(y, 0.f); __syncthreads();
    double a2 = 0.0;
    if (t < 64) {
        for (int i = 0; i < 128; ++i) a2 += (double)shy[i] * (double)W2[i * 64 + t];
        a2 += (double)b2[t];
    }
    red[t] = (t < 64) ? a2 : 0.0; __syncthreads();
    for (int off = 64; off; off >>= 1) { if (t < off) red[t] += red[t + off]; __syncthreads(); }
    double mu2 = red[0] / 64.0; __syncthreads();
    double dv2 = a2 - mu2;
    red[t] = (t < 64) ? dv2 * dv2 : 0.0; __syncthreads();
    for (int off = 64; off; off >>= 1) { if (t < off) red[t] += red[t + off]; __syncthreads(); }
    double var2 = red[0] / 64.0; __syncthreads();
    if (t < 64) {
        float h2 = (float)(dv2 / sqrt(var2 + 1e-5)) * g2[t] + be2[t];
        sh2[t] = fmaxf(h2, 0.f);
    }
    __syncthreads();
    red[t] = (t < 64) ? (double)sh2[t] * (double)W3[t] : 0.0; __syncthreads();
    for (int off = 64; off; off >>= 1) { if (t < off) red[t] += red[t + off]; __syncthreads(); }
    if (t == 0) {
        double zf = red[0] + (double)b3[0];
        out[b] = (float)(1.0 / (1.0 + exp(-zf)));
    }
}

// ---------------------------------------------------------------------------
extern "C" void kernel_launch(void* const* d_in, const int* in_sizes, int n_in,
                              void* d_out, int out_size, void* d_ws, size_t ws_size,
                              hipStream_t stream) {
    (void)n_in; (void)out_size; (void)ws_size;
    const float* x1  = (const float*)d_in[0];
    const int*   ei1 = (const int*)d_in[1];
    const float* x2  = (const float*)d_in[3];
    const int*   ei2 = (const int*)d_in[4];
    const float* W1a = (const float*)d_in[5];
    const float* b1a = (const float*)d_in[6];
    const float* W1b = (const float*)d_in[7];
    const float* b1b = (const float*)d_in[8];
    const float* W2a = (const float*)d_in[9];
    const float* b2a = (const float*)d_in[10];
    const float* W2b = (const float*)d_in[11];
    const float* b2b = (const float*)d_in[12];
    const float* f1W = (const float*)d_in[13];
    const float* f1b = (const float*)d_in[14];
    const float* g1  = (const float*)d_in[15];
    const float* be1 = (const float*)d_in[16];
    const float* f2W = (const float*)d_in[17];
    const float* f2b = (const float*)d_in[18];
    const float* g2  = (const float*)d_in[19];
    const float* be2 = (const float*)d_in[20];
    const float* f3W = (const float*)d_in[21];
    const float* f3b = (const float*)d_in[22];
    float* out = (float*)d_out;

    const int n1 = in_sizes[0] / 128;     // 200000
    const int e1 = in_sizes[1] / 2;       // 2000000
    const int n2 = in_sizes[3] / 128;     // 199
    const int e2 = in_sizes[4] / 2;       // 3184
    const int npg = n1 / 8;               // 25000

    // workspace carve-up
    char* p = (char*)d_ws;
    auto alloc = [&](size_t bytes) { char* r = p; p += (bytes + 255) & ~(size_t)255; return r; };
    float*  A    = (float*)alloc((size_t)n1 * 128 * 4);
    float*  Bb   = (float*)alloc((size_t)n1 * 128 * 4);
    double* sc   = (double*)alloc((size_t)n1 * 8);
    int*    rs1  = (int*)alloc((size_t)(n1 + 1) * 4);   // counts -> row_start (in place)
    int*    cur1 = (int*)alloc((size_t)(n1 + 1) * 4);
    int*    csr1 = (int*)alloc((size_t)e1 * 4);
    int*    bsum = (int*)alloc(4096);
    int*    rs2  = (int*)alloc((size_t)(n2 + 1) * 4);
    int*    cur2 = (int*)alloc((size_t)(n2 + 1) * 4);
    int*    csr2 = (int*)alloc((size_t)e2 * 4);
    float*  G2A  = (float*)alloc((size_t)n2 * 128 * 4);
    float*  G2B  = (float*)alloc((size_t)n2 * 128 * 4);
    float*  o2   = (float*)alloc((size_t)n2 * 64 * 4);
    int*    tk   = (int*)alloc(8 * 50 * 4);
    float*  pld  = (float*)alloc((size_t)8 * 9950 * 4);
    float*  z1   = (float*)alloc(8 * 128 * 4);

    const int* src1 = ei1;           const int* dst1 = ei1 + e1;
    const int* src2 = ei2;           const int* dst2 = ei2 + e2;

    // ---- CSR build (graph1 then graph2; bsum reused, stream-ordered) ----
    hipMemsetAsync(rs1, 0, (size_t)(n1 + 1) * 4, stream);
    hipMemsetAsync(rs2, 0, (size_t)(n2 + 1) * 4, stream);
    hist_kernel<<<(e1 + 255) / 256, 256, 0, stream>>>(dst1, e1, rs1);
    hist_kernel<<<(e2 + 255) / 256, 256, 0, stream>>>(dst2, e2, rs2);
    int tot1 = n1 + 1, nch1 = (tot1 + 1023) / 1024;
    chunksum_kernel<<<nch1, 256, 0, stream>>>(rs1, tot1, bsum);
    scanchunk_kernel<<<1, 256, 0, stream>>>(bsum, nch1, nullptr, bsum, nullptr);
    scanchunk_kernel<<<nch1, 256, 0, stream>>>(rs1, tot1, bsum, rs1, cur1);
    fill_kernel<<<(e1 + 255) / 256, 256, 0, stream>>>(src1, dst1, e1, cur1, csr1);
    int tot2 = n2 + 1, nch2 = (tot2 + 1023) / 1024;
    chunksum_kernel<<<nch2, 256, 0, stream>>>(rs2, tot2, bsum);
    scanchunk_kernel<<<1, 256, 0, stream>>>(bsum, nch2, nullptr, bsum, nullptr);
    scanchunk_kernel<<<nch2, 256, 0, stream>>>(rs2, tot2, bsum, rs2, cur2);
    fill_kernel<<<(e2 + 255) / 256, 256, 0, stream>>>(src2, dst2, e2, cur2, csr2);

    // ---- GIN graph1 ----
    int gb1 = (n1 + 63) / 64;
    gemm_kernel<128, 128, false, false><<<gb1, 256, 0, stream>>>(x1, W1a, nullptr, A, n1);
    agg_kernel<32><<<(n1 + 7) / 8, 256, 0, stream>>>(A, rs1, csr1, b1a, Bb, n1);
    gemm_kernel<128, 128, true, true><<<gb1, 256, 0, stream>>>(Bb, W1b, b1b, A, n1);
    gemm_kernel<128, 64, false, false><<<gb1, 256, 0, stream>>>(A, W2a, nullptr, Bb, n1);
    agg_kernel<16><<<(n1 + 15) / 16, 256, 0, stream>>>(Bb, rs1, csr1, b2a, A, n1);
    gemm_kernel<64, 64, true, true><<<gb1, 256, 0, stream>>>(A, W2b, b2b, Bb, n1);  // out1 = Bb

    // ---- GIN graph2 ----
    int gb2 = (n2 + 63) / 64;
    gemm_kernel<128, 128, false, false><<<gb2, 256, 0, stream>>>(x2, W1a, nullptr, G2A, n2);
    agg_kernel<32><<<(n2 + 7) / 8, 256, 0, stream>>>(G2A, rs2, csr2, b1a, G2B, n2);
    gemm_kernel<128, 128, true, true><<<gb2, 256, 0, stream>>>(G2B, W1b, b1b, G2A, n2);
    gemm_kernel<128, 64, false, false><<<gb2, 256, 0, stream>>>(G2A, W2a, nullptr, G2B, n2);
    agg_kernel<16><<<(n2 + 15) / 16, 256, 0, stream>>>(G2B, rs2, csr2, b2a, G2A, n2);
    gemm_kernel<64, 64, true, true><<<gb2, 256, 0, stream>>>(G2A, W2b, b2b, o2, n2);   // out2

    // ---- scores -> top-50 per graph -> pooled rows ----
    scores_kernel<<<(n1 + 3) / 4, 256, 0, stream>>>(Bb, o2, sc, n1);
    topk_kernel<<<8, 256, 0, stream>>>(sc, tk, npg);
    pooled_kernel<<<400, 256, 0, stream>>>(Bb, o2, tk, pld, npg);

    // ---- head ----
    fc1_kernel<<<32, 256, 0, stream>>>(pld, f1W, f1b, z1);
    head_kernel<<<8, 128, 0, stream>>>(z1, g1, be1, f2W, f2b, g2, be2, f3W, f3b, out);
}

// Round 2
// 1757.862 us; speedup vs baseline: 1.4063x; 1.4063x over previous
//
#include <hip/hip_runtime.h>
#include <math.h>

// ---------------------------------------------------------------------------
// SiameseGNN_GIN: GIN(x1) & GIN(x2) -> cdist -> sort-pool(k=50 by last col)
// -> fc1+LN+ReLU -> fc2+LN+ReLU -> fc3+sigmoid
// Key restructure: (x+agg)@W = x@W + A*(x@W)  => aggregate AFTER the linear,
// so conv2's aggregation is 64-wide. CSR (by dst) gather instead of atomics.
// Distance matrix never materialized: scores (col 198) -> top-50 -> 400 rows.
// R2: two-phase LDS top-k (R1's single-block global-memory version was 891 us
// latency-bound at 0.4% occupancy).
// ---------------------------------------------------------------------------

#define CPB 64   // chunk-blocks per graph in top-k phase A

// ---------------- CSR build ----------------
__global__ __launch_bounds__(256) void hist_kernel(const int* __restrict__ dst, int E,
                                                   int* __restrict__ counts) {
    int e = blockIdx.x * 256 + threadIdx.x;
    if (e < E) atomicAdd(&counts[dst[e]], 1);
}

__global__ __launch_bounds__(256) void chunksum_kernel(const int* __restrict__ in, int total,
                                                       int* __restrict__ bsum) {
    __shared__ int red[256];
    int t = threadIdx.x;
    int base = blockIdx.x * 1024 + t * 4;
    int s = 0;
#pragma unroll
    for (int j = 0; j < 4; ++j) { int i = base + j; if (i < total) s += in[i]; }
    red[t] = s; __syncthreads();
    for (int off = 128; off; off >>= 1) { if (t < off) red[t] += red[t + off]; __syncthreads(); }
    if (t == 0) bsum[blockIdx.x] = red[0];
}

// exclusive scan of 1024-chunks; chunk base from baseArr (or 0). Optionally dup to out2.
__global__ __launch_bounds__(256) void scanchunk_kernel(const int* __restrict__ in, int total,
                                                        const int* __restrict__ baseArr,
                                                        int* __restrict__ out,
                                                        int* __restrict__ out2) {
    __shared__ int tsum[256];
    int t = threadIdx.x;
    int base_i = blockIdx.x * 1024 + t * 4;
    int v[4];
#pragma unroll
    for (int j = 0; j < 4; ++j) v[j] = (base_i + j < total) ? in[base_i + j] : 0;
    int l0 = 0, l1 = v[0], l2 = v[0] + v[1], l3 = l2 + v[2];
    int s = l3 + v[3];
    tsum[t] = s; __syncthreads();
    for (int off = 1; off < 256; off <<= 1) {
        int x = (t >= off) ? tsum[t - off] : 0;
        __syncthreads();
        tsum[t] += x;
        __syncthreads();
    }
    int cb = baseArr ? baseArr[blockIdx.x] : 0;
    int te = cb + tsum[t] - s;
    int outs[4] = { te + l0, te + l1, te + l2, te + l3 };
#pragma unroll
    for (int j = 0; j < 4; ++j) {
        int i = base_i + j;
        if (i < total) { out[i] = outs[j]; if (out2) out2[i] = outs[j]; }
    }
}

__global__ __launch_bounds__(256) void fill_kernel(const int* __restrict__ src,
                                                   const int* __restrict__ dst, int E,
                                                   int* __restrict__ cur, int* __restrict__ csr) {
    int e = blockIdx.x * 256 + threadIdx.x;
    if (e < E) {
        int d = dst[e];
        int p = atomicAdd(&cur[d], 1);
        csr[p] = src[e];
    }
}

// ---------------- fp32 GEMM: Y[N,KO] = relu?(X[N,KI] @ W[KI,KO] + bias?) ----------------
template <int KI, int KO, bool BIAS, bool RELU>
__global__ __launch_bounds__(256) void gemm_kernel(const float* __restrict__ X,
                                                   const float* __restrict__ Wm,
                                                   const float* __restrict__ bias,
                                                   float* __restrict__ Y, int N) {
    constexpr int TPR = KO / 4;       // threads across columns (float4 cols)
    constexpr int RPT = KO / 16;      // rows per thread (8 for KO=128, 4 for KO=64)
    constexpr int XS = 68;            // 64 rows + 4 pad (keeps 16B alignment)
    __shared__ __align__(16) float wl[32 * KO];
    __shared__ __align__(16) float xt[32 * XS];
    const int t = threadIdx.x;
    const int r0 = blockIdx.x * 64;
    const int tx = t % TPR, ty = t / TPR;
    float4 acc[RPT];
#pragma unroll
    for (int r = 0; r < RPT; ++r) acc[r] = make_float4(0.f, 0.f, 0.f, 0.f);

    for (int kb = 0; kb < KI; kb += 32) {
        __syncthreads();
#pragma unroll
        for (int i = t; i < 32 * KO / 4; i += 256)
            ((float4*)wl)[i] = ((const float4*)Wm)[kb * KO / 4 + i];
#pragma unroll
        for (int L = t; L < 512; L += 256) {
            int row = L >> 3, kq = L & 7;
            int gr = r0 + row;
            float4 v = make_float4(0.f, 0.f, 0.f, 0.f);
            if (gr < N) v = *(const float4*)(X + (size_t)gr * KI + kb + kq * 4);
            xt[(kq * 4 + 0) * XS + row] = v.x;
            xt[(kq * 4 + 1) * XS + row] = v.y;
            xt[(kq * 4 + 2) * XS + row] = v.z;
            xt[(kq * 4 + 3) * XS + row] = v.w;
        }
        __syncthreads();
#pragma unroll
        for (int k = 0; k < 32; ++k) {
            float4 wv = ((const float4*)wl)[k * TPR + tx];
            const float4* xp = (const float4*)(xt + k * XS + ty * RPT);
#pragma unroll
            for (int rq = 0; rq < RPT / 4; ++rq) {
                float4 xv = xp[rq];
                acc[rq*4+0].x += xv.x * wv.x; acc[rq*4+0].y += xv.x * wv.y;
                acc[rq*4+0].z += xv.x * wv.z; acc[rq*4+0].w += xv.x * wv.w;
                acc[rq*4+1].x += xv.y * wv.x; acc[rq*4+1].y += xv.y * wv.y;
                acc[rq*4+1].z += xv.y * wv.z; acc[rq*4+1].w += xv.y * wv.w;
                acc[rq*4+2].x += xv.z * wv.x; acc[rq*4+2].y += xv.z * wv.y;
                acc[rq*4+2].z += xv.z * wv.z; acc[rq*4+2].w += xv.z * wv.w;
                acc[rq*4+3].x += xv.w * wv.x; acc[rq*4+3].y += xv.w * wv.y;
                acc[rq*4+3].z += xv.w * wv.z; acc[rq*4+3].w += xv.w * wv.w;
            }
        }
    }
    float4 b4 = make_float4(0.f, 0.f, 0.f, 0.f);
    if (BIAS) b4 = ((const float4*)bias)[tx];
#pragma unroll
    for (int r = 0; r < RPT; ++r) {
        int gr = r0 + ty * RPT + r;
        if (gr < N) {
            float4 o = make_float4(acc[r].x + b4.x, acc[r].y + b4.y,
                                   acc[r].z + b4.z, acc[r].w + b4.w);
            if (RELU) {
                o.x = fmaxf(o.x, 0.f); o.y = fmaxf(o.y, 0.f);
                o.z = fmaxf(o.z, 0.f); o.w = fmaxf(o.w, 0.f);
            }
            *(float4*)(Y + (size_t)gr * KO + tx * 4) = o;
        }
    }
}

// ---------------- aggregation: out[n] = relu(x[n] + sum_{e:dst=n} x[src] + bias) -------
template <int VEC>  // float4s per row: 32 (width 128) or 16 (width 64)
__global__ __launch_bounds__(256) void agg_kernel(const float* __restrict__ x,
                                                  const int* __restrict__ rs,
                                                  const int* __restrict__ csr,
                                                  const float* __restrict__ bias,
                                                  float* __restrict__ out, int N) {
    const int NPB = 256 / VEC;
    const int t = threadIdx.x;
    const int node = blockIdx.x * NPB + t / VEC;
    const int c = t % VEC;
    if (node >= N) return;
    const int W = VEC * 4;
    float4 acc = ((const float4*)(x + (size_t)node * W))[c];
    const int s1 = rs[node + 1];
    for (int k = rs[node]; k < s1; ++k) {
        int src = csr[k];
        float4 v = ((const float4*)(x + (size_t)src * W))[c];
        acc.x += v.x; acc.y += v.y; acc.z += v.z; acc.w += v.w;
    }
    float4 b4 = ((const float4*)bias)[c];
    acc.x = fmaxf(acc.x + b4.x, 0.f);
    acc.y = fmaxf(acc.y + b4.y, 0.f);
    acc.z = fmaxf(acc.z + b4.z, 0.f);
    acc.w = fmaxf(acc.w + b4.w, 0.f);
    ((float4*)(out + (size_t)node * W))[c] = acc;
}

// ---------------- scores: d(out1[n], out2[198]) via cdist formula, fp64 ----------------
__global__ __launch_bounds__(256) void scores_kernel(const float* __restrict__ out1,
                                                     const float* __restrict__ out2,
                                                     double* __restrict__ sc, int N) {
    const int t = threadIdx.x;
    const int node = blockIdx.x * 4 + (t >> 6);
    const int lane = t & 63;
    if (node >= N) return;
    float a = out1[(size_t)node * 64 + lane];
    float bv = out2[198 * 64 + lane];
    double na = (double)a * a;
    double nb = (double)bv * bv;
    double dd = (double)a * bv;
    for (int off = 32; off; off >>= 1) {
        na += __shfl_xor(na, off);
        nb += __shfl_xor(nb, off);
        dd += __shfl_xor(dd, off);
    }
    if (lane == 0) {
        double sq = na + nb - 2.0 * dd;
        sc[node] = (sq > 0.0) ? sqrt(sq) : 0.0;
    }
}

// ---------------- top-50 phase A: per-chunk top-50 into candidate list -----------------
// grid = B * CPB blocks; chunk = ceil(npg/CPB) (391 for npg=25000; LDS sized 400)
__global__ __launch_bounds__(256) void topkA_kernel(const double* __restrict__ sc,
                                                    double* __restrict__ cv,
                                                    int* __restrict__ ci, int npg) {
    const int g = blockIdx.x / CPB, cb = blockIdx.x % CPB;
    const int chunk = (npg + CPB - 1) / CPB;
    const int base = cb * chunk;
    const int len = (npg - base < chunk) ? (npg - base) : chunk;
    const int t = threadIdx.x;
    __shared__ double lv[400];
    __shared__ double wvs[4];
    __shared__ int wss[4];
    const double* s = sc + (size_t)g * npg;
    for (int i = t; i < chunk; i += 256)
        lv[i] = (i < len) ? s[base + i] : -1.0e300;
    __syncthreads();
    const int ob = (g * CPB + cb) * 50;
    for (int r = 0; r < 50; ++r) {
        double bv = -1.0e300; int bs = 0x3fffffff;
        for (int i = t; i < chunk; i += 256) {
            double v = lv[i];
            if (v > bv || (v == bv && i < bs)) { bv = v; bs = i; }
        }
#pragma unroll
        for (int off = 32; off; off >>= 1) {
            double ov = __shfl_xor(bv, off);
            int os = __shfl_xor(bs, off);
            if (ov > bv || (ov == bv && os < bs)) { bv = ov; bs = os; }
        }
        if ((t & 63) == 0) { wvs[t >> 6] = bv; wss[t >> 6] = bs; }
        __syncthreads();
        if (t == 0) {
#pragma unroll
            for (int w = 1; w < 4; ++w)
                if (wvs[w] > bv || (wvs[w] == bv && wss[w] < bs)) { bv = wvs[w]; bs = wss[w]; }
            cv[ob + r] = bv;
            ci[ob + r] = base + bs;
            lv[bs] = -1.0e300;
        }
        __syncthreads();
    }
}

// ---------------- top-50 phase B: top-50 of CPB*50 candidates per graph ----------------
__global__ __launch_bounds__(256) void topkB_kernel(const double* __restrict__ cv,
                                                    const int* __restrict__ ci,
                                                    int* __restrict__ topk) {
    const int g = blockIdx.x, t = threadIdx.x;
    const int M = CPB * 50;   // 3200
    __shared__ double lv[CPB * 50];
    __shared__ int li[CPB * 50];
    __shared__ double wvs[4];
    __shared__ int wis[4], wss[4];
    for (int i = t; i < M; i += 256) {
        lv[i] = cv[(size_t)g * M + i];
        li[i] = ci[(size_t)g * M + i];
    }
    __syncthreads();
    for (int r = 0; r < 50; ++r) {
        double bv = -1.0e300; int bi = 0x3fffffff, bs = 0;
        for (int i = t; i < M; i += 256) {
            double v = lv[i]; int idx = li[i];
            if (v > bv || (v == bv && idx < bi)) { bv = v; bi = idx; bs = i; }
        }
#pragma unroll
        for (int off = 32; off; off >>= 1) {
            double ov = __shfl_xor(bv, off);
            int oi = __shfl_xor(bi, off);
            int os = __shfl_xor(bs, off);
            if (ov > bv || (ov == bv && oi < bi)) { bv = ov; bi = oi; bs = os; }
        }
        if ((t & 63) == 0) { wvs[t >> 6] = bv; wis[t >> 6] = bi; wss[t >> 6] = bs; }
        __syncthreads();
        if (t == 0) {
#pragma unroll
            for (int w = 1; w < 4; ++w)
                if (wvs[w] > bv || (wvs[w] == bv && wis[w] < bi)) {
                    bv = wvs[w]; bi = wis[w]; bs = wss[w];
                }
            topk[g * 50 + r] = bi;
            lv[bs] = -1.0e300;
        }
        __syncthreads();
    }
}

// ---------------- pooled rows: d(out1[sel], out2[j]) for 400 rows x 199 cols -----------
__global__ __launch_bounds__(256) void pooled_kernel(const float* __restrict__ out1,
                                                     const float* __restrict__ out2,
                                                     const int* __restrict__ topk,
                                                     float* __restrict__ pooled, int npg) {
    const int bk = blockIdx.x;           // 0..399
    const int g = bk / 50, kk = bk % 50;
    __shared__ float arow[64];
    const int t = threadIdx.x;
    const int node = g * npg + topk[g * 50 + kk];
    if (t < 64) arow[t] = out1[(size_t)node * 64 + t];
    __syncthreads();
    if (t < 199) {
        double na = 0.0, nb = 0.0, dd = 0.0;
        for (int k2 = 0; k2 < 64; ++k2) {
            double a = arow[k2];
            double b = out2[t * 64 + k2];
            na += a * a; nb += b * b; dd += a * b;
        }
        double sq = na + nb - 2.0 * dd;
        pooled[(size_t)g * 9950 + kk * 199 + t] = (float)((sq > 0.0) ? sqrt(sq) : 0.0);
    }
}

// ---------------- fc1: z1[b,f] = pooled[b,:] @ fc1_W[:,f] + b, 8-way k-split ----------
__global__ __launch_bounds__(256) void fc1_kernel(const float* __restrict__ pooled,
                                                  const float* __restrict__ W,
                                                  const float* __restrict__ bias,
                                                  float* __restrict__ z1) {
    const int b = blockIdx.x >> 2, fg = blockIdx.x & 3;
    const int t = threadIdx.x;
    const int f = fg * 32 + (t & 31);
    const int ks = t >> 5;
    const float* p = pooled + (size_t)b * 9950;
    double acc = 0.0;
    for (int i = ks; i < 9950; i += 8)
        acc += (double)p[i] * (double)W[(size_t)i * 128 + f];
    __shared__ double red[256];
    red[t] = acc; __syncthreads();
    for (int off = 4; off; off >>= 1) {
        if (ks < off) red[t] += red[t + off * 32];
        __syncthreads();
    }
    if (ks == 0) z1[b * 128 + f] = (float)(red[t] + (double)bias[f]);
}

// ---------------- head: LN+ReLU, fc2, LN+ReLU, fc3, sigmoid ---------------------------
__global__ __launch_bounds__(128) void head_kernel(const float* __restrict__ z1,
                                                   const float* __restrict__ g1,
                                                   const float* __restrict__ be1,
                                                   const float* __restrict__ W2,
                                                   const float* __restrict__ b2,
                                                   const float* __restrict__ g2,
                                                   const float* __restrict__ be2,
                                                   const float* __restrict__ W3,
                                                   const float* __restrict__ b3,
                                                   float* __restrict__ out) {
    const int b = blockIdx.x, t = threadIdx.x;
    __shared__ double red[128];
    __shared__ float shy[128];
    __shared__ float sh2[64];
    float z = z1[b * 128 + t];
    red[t] = z; __syncthreads();
    for (int off = 64; off; off >>= 1) { if (t < off) red[t] += red[t + off]; __syncthreads(); }
    double mu = red[0] / 128.0; __syncthreads();
    double dv = (double)z - mu;
    red[t] = dv * dv; __syncthreads();
    for (int off = 64; off; off >>= 1) { if (t < off) red[t] += red[t + off]; __syncthreads(); }
    double var = red[0] / 128.0; __syncthreads();
    float y = (float)(dv / sqrt(var + 1e-5)) * g1[t] + be1[t];
    shy[t] = fmaxf(y, 0.f); __syncthreads();
    double a2 = 0.0;
    if (t < 64) {
        for (int i = 0; i < 128; ++i) a2 += (double)shy[i] * (double)W2[i * 64 + t];
        a2 += (double)b2[t];
    }
    red[t] = (t < 64) ? a2 : 0.0; __syncthreads();
    for (int off = 64; off; off >>= 1) { if (t < off) red[t] += red[t + off]; __syncthreads(); }
    double mu2 = red[0] / 64.0; __syncthreads();
    double dv2 = a2 - mu2;
    red[t] = (t < 64) ? dv2 * dv2 : 0.0; __syncthreads();
    for (int off = 64; off; off >>= 1) { if (t < off) red[t] += red[t + off]; __syncthreads(); }
    double var2 = red[0] / 64.0; __syncthreads();
    if (t < 64) {
        float h2 = (float)(dv2 / sqrt(var2 + 1e-5)) * g2[t] + be2[t];
        sh2[t] = fmaxf(h2, 0.f);
    }
    __syncthreads();
    red[t] = (t < 64) ? (double)sh2[t] * (double)W3[t] : 0.0; __syncthreads();
    for (int off = 64; off; off >>= 1) { if (t < off) red[t] += red[t + off]; __syncthreads(); }
    if (t == 0) {
        double zf = red[0] + (double)b3[0];
        out[b] = (float)(1.0 / (1.0 + exp(-zf)));
    }
}

// ---------------------------------------------------------------------------
extern "C" void kernel_launch(void* const* d_in, const int* in_sizes, int n_in,
                              void* d_out, int out_size, void* d_ws, size_t ws_size,
                              hipStream_t stream) {
    (void)n_in; (void)out_size; (void)ws_size;
    const float* x1  = (const float*)d_in[0];
    const int*   ei1 = (const int*)d_in[1];
    const float* x2  = (const float*)d_in[3];
    const int*   ei2 = (const int*)d_in[4];
    const float* W1a = (const float*)d_in[5];
    const float* b1a = (const float*)d_in[6];
    const float* W1b = (const float*)d_in[7];
    const float* b1b = (const float*)d_in[8];
    const float* W2a = (const float*)d_in[9];
    const float* b2a = (const float*)d_in[10];
    const float* W2b = (const float*)d_in[11];
    const float* b2b = (const float*)d_in[12];
    const float* f1W = (const float*)d_in[13];
    const float* f1b = (const float*)d_in[14];
    const float* g1  = (const float*)d_in[15];
    const float* be1 = (const float*)d_in[16];
    const float* f2W = (const float*)d_in[17];
    const float* f2b = (const float*)d_in[18];
    const float* g2  = (const float*)d_in[19];
    const float* be2 = (const float*)d_in[20];
    const float* f3W = (const float*)d_in[21];
    const float* f3b = (const float*)d_in[22];
    float* out = (float*)d_out;

    const int n1 = in_sizes[0] / 128;     // 200000
    const int e1 = in_sizes[1] / 2;       // 2000000
    const int n2 = in_sizes[3] / 128;     // 199
    const int e2 = in_sizes[4] / 2;       // 3184
    const int npg = n1 / 8;               // 25000

    // workspace carve-up
    char* p = (char*)d_ws;
    auto alloc = [&](size_t bytes) { char* r = p; p += (bytes + 255) & ~(size_t)255; return r; };
    float*  A    = (float*)alloc((size_t)n1 * 128 * 4);
    float*  Bb   = (float*)alloc((size_t)n1 * 128 * 4);
    double* sc   = (double*)alloc((size_t)n1 * 8);
    int*    rs1  = (int*)alloc((size_t)(n1 + 1) * 4);   // counts -> row_start (in place)
    int*    cur1 = (int*)alloc((size_t)(n1 + 1) * 4);
    int*    csr1 = (int*)alloc((size_t)e1 * 4);
    int*    bsum = (int*)alloc(4096);
    int*    rs2  = (int*)alloc((size_t)(n2 + 1) * 4);
    int*    cur2 = (int*)alloc((size_t)(n2 + 1) * 4);
    int*    csr2 = (int*)alloc((size_t)e2 * 4);
    float*  G2A  = (float*)alloc((size_t)n2 * 128 * 4);
    float*  G2B  = (float*)alloc((size_t)n2 * 128 * 4);
    float*  o2   = (float*)alloc((size_t)n2 * 64 * 4);
    double* cndv = (double*)alloc((size_t)8 * CPB * 50 * 8);
    int*    cndi = (int*)alloc((size_t)8 * CPB * 50 * 4);
    int*    tk   = (int*)alloc(8 * 50 * 4);
    float*  pld  = (float*)alloc((size_t)8 * 9950 * 4);
    float*  z1   = (float*)alloc(8 * 128 * 4);

    const int* src1 = ei1;           const int* dst1 = ei1 + e1;
    const int* src2 = ei2;           const int* dst2 = ei2 + e2;

    // ---- CSR build (graph1 then graph2; bsum reused, stream-ordered) ----
    hipMemsetAsync(rs1, 0, (size_t)(n1 + 1) * 4, stream);
    hipMemsetAsync(rs2, 0, (size_t)(n2 + 1) * 4, stream);
    hist_kernel<<<(e1 + 255) / 256, 256, 0, stream>>>(dst1, e1, rs1);
    hist_kernel<<<(e2 + 255) / 256, 256, 0, stream>>>(dst2, e2, rs2);
    int tot1 = n1 + 1, nch1 = (tot1 + 1023) / 1024;
    chunksum_kernel<<<nch1, 256, 0, stream>>>(rs1, tot1, bsum);
    scanchunk_kernel<<<1, 256, 0, stream>>>(bsum, nch1, nullptr, bsum, nullptr);
    scanchunk_kernel<<<nch1, 256, 0, stream>>>(rs1, tot1, bsum, rs1, cur1);
    fill_kernel<<<(e1 + 255) / 256, 256, 0, stream>>>(src1, dst1, e1, cur1, csr1);
    int tot2 = n2 + 1, nch2 = (tot2 + 1023) / 1024;
    chunksum_kernel<<<nch2, 256, 0, stream>>>(rs2, tot2, bsum);
    scanchunk_kernel<<<1, 256, 0, stream>>>(bsum, nch2, nullptr, bsum, nullptr);
    scanchunk_kernel<<<nch2, 256, 0, stream>>>(rs2, tot2, bsum, rs2, cur2);
    fill_kernel<<<(e2 + 255) / 256, 256, 0, stream>>>(src2, dst2, e2, cur2, csr2);

    // ---- GIN graph1 ----
    int gb1 = (n1 + 63) / 64;
    gemm_kernel<128, 128, false, false><<<gb1, 256, 0, stream>>>(x1, W1a, nullptr, A, n1);
    agg_kernel<32><<<(n1 + 7) / 8, 256, 0, stream>>>(A, rs1, csr1, b1a, Bb, n1);
    gemm_kernel<128, 128, true, true><<<gb1, 256, 0, stream>>>(Bb, W1b, b1b, A, n1);
    gemm_kernel<128, 64, false, false><<<gb1, 256, 0, stream>>>(A, W2a, nullptr, Bb, n1);
    agg_kernel<16><<<(n1 + 15) / 16, 256, 0, stream>>>(Bb, rs1, csr1, b2a, A, n1);
    gemm_kernel<64, 64, true, true><<<gb1, 256, 0, stream>>>(A, W2b, b2b, Bb, n1);  // out1 = Bb

    // ---- GIN graph2 ----
    int gb2 = (n2 + 63) / 64;
    gemm_kernel<128, 128, false, false><<<gb2, 256, 0, stream>>>(x2, W1a, nullptr, G2A, n2);
    agg_kernel<32><<<(n2 + 7) / 8, 256, 0, stream>>>(G2A, rs2, csr2, b1a, G2B, n2);
    gemm_kernel<128, 128, true, true><<<gb2, 256, 0, stream>>>(G2B, W1b, b1b, G2A, n2);
    gemm_kernel<128, 64, false, false><<<gb2, 256, 0, stream>>>(G2A, W2a, nullptr, G2B, n2);
    agg_kernel<16><<<(n2 + 15) / 16, 256, 0, stream>>>(G2B, rs2, csr2, b2a, G2A, n2);
    gemm_kernel<64, 64, true, true><<<gb2, 256, 0, stream>>>(G2A, W2b, b2b, o2, n2);   // out2

    // ---- scores -> two-phase top-50 per graph -> pooled rows ----
    scores_kernel<<<(n1 + 3) / 4, 256, 0, stream>>>(Bb, o2, sc, n1);
    topkA_kernel<<<8 * CPB, 256, 0, stream>>>(sc, cndv, cndi, npg);
    topkB_kernel<<<8, 256, 0, stream>>>(cndv, cndi, tk);
    pooled_kernel<<<400, 256, 0, stream>>>(Bb, o2, tk, pld, npg);

    // ---- head ----
    fc1_kernel<<<32, 256, 0, stream>>>(pld, f1W, f1b, z1);
    head_kernel<<<8, 128, 0, stream>>>(z1, g1, be1, f2W, f2b, g2, be2, f3W, f3b, out);
}

// Round 3
// 1310.233 us; speedup vs baseline: 1.8867x; 1.3416x over previous
//
#include <hip/hip_runtime.h>
#include <math.h>

// ---------------------------------------------------------------------------
// SiameseGNN_GIN: GIN(x1) & GIN(x2) -> cdist -> sort-pool(k=50 by last col)
// -> fc1+LN+ReLU -> fc2+LN+ReLU -> fc3+sigmoid
// Key restructure: (x+agg)@W = x@W + A*(x@W)  => aggregate AFTER the linear,
// so conv2's aggregation is 64-wide. CSR (by dst) gather instead of atomics.
// Distance matrix never materialized: scores (col 198) -> top-50 -> 400 rows.
// R2: two-phase LDS top-k (R1: 891 us latency-bound at 0.4% occupancy).
// R3: k-split fc1 (R2: 474 us latency-bound, 32 blocks x 1244-iter serial
// loops with 4KB-stride W walk -> 512 blocks x 78-iter coalesced + reduce).
// ---------------------------------------------------------------------------

#define CPB 64   // chunk-blocks per graph in top-k phase A
#define FKS 64   // k-split chunks for fc1

// ---------------- CSR build ----------------
__global__ __launch_bounds__(256) void hist_kernel(const int* __restrict__ dst, int E,
                                                   int* __restrict__ counts) {
    int e = blockIdx.x * 256 + threadIdx.x;
    if (e < E) atomicAdd(&counts[dst[e]], 1);
}

__global__ __launch_bounds__(256) void chunksum_kernel(const int* __restrict__ in, int total,
                                                       int* __restrict__ bsum) {
    __shared__ int red[256];
    int t = threadIdx.x;
    int base = blockIdx.x * 1024 + t * 4;
    int s = 0;
#pragma unroll
    for (int j = 0; j < 4; ++j) { int i = base + j; if (i < total) s += in[i]; }
    red[t] = s; __syncthreads();
    for (int off = 128; off; off >>= 1) { if (t < off) red[t] += red[t + off]; __syncthreads(); }
    if (t == 0) bsum[blockIdx.x] = red[0];
}

// exclusive scan of 1024-chunks; chunk base from baseArr (or 0). Optionally dup to out2.
__global__ __launch_bounds__(256) void scanchunk_kernel(const int* __restrict__ in, int total,
                                                        const int* __restrict__ baseArr,
                                                        int* __restrict__ out,
                                                        int* __restrict__ out2) {
    __shared__ int tsum[256];
    int t = threadIdx.x;
    int base_i = blockIdx.x * 1024 + t * 4;
    int v[4];
#pragma unroll
    for (int j = 0; j < 4; ++j) v[j] = (base_i + j < total) ? in[base_i + j] : 0;
    int l0 = 0, l1 = v[0], l2 = v[0] + v[1], l3 = l2 + v[2];
    int s = l3 + v[3];
    tsum[t] = s; __syncthreads();
    for (int off = 1; off < 256; off <<= 1) {
        int x = (t >= off) ? tsum[t - off] : 0;
        __syncthreads();
        tsum[t] += x;
        __syncthreads();
    }
    int cb = baseArr ? baseArr[blockIdx.x] : 0;
    int te = cb + tsum[t] - s;
    int outs[4] = { te + l0, te + l1, te + l2, te + l3 };
#pragma unroll
    for (int j = 0; j < 4; ++j) {
        int i = base_i + j;
        if (i < total) { out[i] = outs[j]; if (out2) out2[i] = outs[j]; }
    }
}

__global__ __launch_bounds__(256) void fill_kernel(const int* __restrict__ src,
                                                   const int* __restrict__ dst, int E,
                                                   int* __restrict__ cur, int* __restrict__ csr) {
    int e = blockIdx.x * 256 + threadIdx.x;
    if (e < E) {
        int d = dst[e];
        int p = atomicAdd(&cur[d], 1);
        csr[p] = src[e];
    }
}

// ---------------- fp32 GEMM: Y[N,KO] = relu?(X[N,KI] @ W[KI,KO] + bias?) ----------------
template <int KI, int KO, bool BIAS, bool RELU>
__global__ __launch_bounds__(256) void gemm_kernel(const float* __restrict__ X,
                                                   const float* __restrict__ Wm,
                                                   const float* __restrict__ bias,
                                                   float* __restrict__ Y, int N) {
    constexpr int TPR = KO / 4;       // threads across columns (float4 cols)
    constexpr int RPT = KO / 16;      // rows per thread (8 for KO=128, 4 for KO=64)
    constexpr int XS = 68;            // 64 rows + 4 pad (keeps 16B alignment)
    __shared__ __align__(16) float wl[32 * KO];
    __shared__ __align__(16) float xt[32 * XS];
    const int t = threadIdx.x;
    const int r0 = blockIdx.x * 64;
    const int tx = t % TPR, ty = t / TPR;
    float4 acc[RPT];
#pragma unroll
    for (int r = 0; r < RPT; ++r) acc[r] = make_float4(0.f, 0.f, 0.f, 0.f);

    for (int kb = 0; kb < KI; kb += 32) {
        __syncthreads();
#pragma unroll
        for (int i = t; i < 32 * KO / 4; i += 256)
            ((float4*)wl)[i] = ((const float4*)Wm)[kb * KO / 4 + i];
#pragma unroll
        for (int L = t; L < 512; L += 256) {
            int row = L >> 3, kq = L & 7;
            int gr = r0 + row;
            float4 v = make_float4(0.f, 0.f, 0.f, 0.f);
            if (gr < N) v = *(const float4*)(X + (size_t)gr * KI + kb + kq * 4);
            xt[(kq * 4 + 0) * XS + row] = v.x;
            xt[(kq * 4 + 1) * XS + row] = v.y;
            xt[(kq * 4 + 2) * XS + row] = v.z;
            xt[(kq * 4 + 3) * XS + row] = v.w;
        }
        __syncthreads();
#pragma unroll
        for (int k = 0; k < 32; ++k) {
            float4 wv = ((const float4*)wl)[k * TPR + tx];
            const float4* xp = (const float4*)(xt + k * XS + ty * RPT);
#pragma unroll
            for (int rq = 0; rq < RPT / 4; ++rq) {
                float4 xv = xp[rq];
                acc[rq*4+0].x += xv.x * wv.x; acc[rq*4+0].y += xv.x * wv.y;
                acc[rq*4+0].z += xv.x * wv.z; acc[rq*4+0].w += xv.x * wv.w;
                acc[rq*4+1].x += xv.y * wv.x; acc[rq*4+1].y += xv.y * wv.y;
                acc[rq*4+1].z += xv.y * wv.z; acc[rq*4+1].w += xv.y * wv.w;
                acc[rq*4+2].x += xv.z * wv.x; acc[rq*4+2].y += xv.z * wv.y;
                acc[rq*4+2].z += xv.z * wv.z; acc[rq*4+2].w += xv.z * wv.w;
                acc[rq*4+3].x += xv.w * wv.x; acc[rq*4+3].y += xv.w * wv.y;
                acc[rq*4+3].z += xv.w * wv.z; acc[rq*4+3].w += xv.w * wv.w;
            }
        }
    }
    float4 b4 = make_float4(0.f, 0.f, 0.f, 0.f);
    if (BIAS) b4 = ((const float4*)bias)[tx];
#pragma unroll
    for (int r = 0; r < RPT; ++r) {
        int gr = r0 + ty * RPT + r;
        if (gr < N) {
            float4 o = make_float4(acc[r].x + b4.x, acc[r].y + b4.y,
                                   acc[r].z + b4.z, acc[r].w + b4.w);
            if (RELU) {
                o.x = fmaxf(o.x, 0.f); o.y = fmaxf(o.y, 0.f);
                o.z = fmaxf(o.z, 0.f); o.w = fmaxf(o.w, 0.f);
            }
            *(float4*)(Y + (size_t)gr * KO + tx * 4) = o;
        }
    }
}

// ---------------- aggregation: out[n] = relu(x[n] + sum_{e:dst=n} x[src] + bias) -------
template <int VEC>  // float4s per row: 32 (width 128) or 16 (width 64)
__global__ __launch_bounds__(256) void agg_kernel(const float* __restrict__ x,
                                                  const int* __restrict__ rs,
                                                  const int* __restrict__ csr,
                                                  const float* __restrict__ bias,
                                                  float* __restrict__ out, int N) {
    const int NPB = 256 / VEC;
    const int t = threadIdx.x;
    const int node = blockIdx.x * NPB + t / VEC;
    const int c = t % VEC;
    if (node >= N) return;
    const int W = VEC * 4;
    float4 acc = ((const float4*)(x + (size_t)node * W))[c];
    const int s1 = rs[node + 1];
    for (int k = rs[node]; k < s1; ++k) {
        int src = csr[k];
        float4 v = ((const float4*)(x + (size_t)src * W))[c];
        acc.x += v.x; acc.y += v.y; acc.z += v.z; acc.w += v.w;
    }
    float4 b4 = ((const float4*)bias)[c];
    acc.x = fmaxf(acc.x + b4.x, 0.f);
    acc.y = fmaxf(acc.y + b4.y, 0.f);
    acc.z = fmaxf(acc.z + b4.z, 0.f);
    acc.w = fmaxf(acc.w + b4.w, 0.f);
    ((float4*)(out + (size_t)node * W))[c] = acc;
}

// ---------------- scores: d(out1[n], out2[198]) via cdist formula, fp64 ----------------
__global__ __launch_bounds__(256) void scores_kernel(const float* __restrict__ out1,
                                                     const float* __restrict__ out2,
                                                     double* __restrict__ sc, int N) {
    const int t = threadIdx.x;
    const int node = blockIdx.x * 4 + (t >> 6);
    const int lane = t & 63;
    if (node >= N) return;
    float a = out1[(size_t)node * 64 + lane];
    float bv = out2[198 * 64 + lane];
    double na = (double)a * a;
    double nb = (double)bv * bv;
    double dd = (double)a * bv;
    for (int off = 32; off; off >>= 1) {
        na += __shfl_xor(na, off);
        nb += __shfl_xor(nb, off);
        dd += __shfl_xor(dd, off);
    }
    if (lane == 0) {
        double sq = na + nb - 2.0 * dd;
        sc[node] = (sq > 0.0) ? sqrt(sq) : 0.0;
    }
}

// ---------------- top-50 phase A: per-chunk top-50 into candidate list -----------------
// grid = B * CPB blocks; chunk = ceil(npg/CPB) (391 for npg=25000; LDS sized 400)
__global__ __launch_bounds__(256) void topkA_kernel(const double* __restrict__ sc,
                                                    double* __restrict__ cv,
                                                    int* __restrict__ ci, int npg) {
    const int g = blockIdx.x / CPB, cb = blockIdx.x % CPB;
    const int chunk = (npg + CPB - 1) / CPB;
    const int base = cb * chunk;
    const int len = (npg - base < chunk) ? (npg - base) : chunk;
    const int t = threadIdx.x;
    __shared__ double lv[400];
    __shared__ double wvs[4];
    __shared__ int wss[4];
    const double* s = sc + (size_t)g * npg;
    for (int i = t; i < chunk; i += 256)
        lv[i] = (i < len) ? s[base + i] : -1.0e300;
    __syncthreads();
    const int ob = (g * CPB + cb) * 50;
    for (int r = 0; r < 50; ++r) {
        double bv = -1.0e300; int bs = 0x3fffffff;
        for (int i = t; i < chunk; i += 256) {
            double v = lv[i];
            if (v > bv || (v == bv && i < bs)) { bv = v; bs = i; }
        }
#pragma unroll
        for (int off = 32; off; off >>= 1) {
            double ov = __shfl_xor(bv, off);
            int os = __shfl_xor(bs, off);
            if (ov > bv || (ov == bv && os < bs)) { bv = ov; bs = os; }
        }
        if ((t & 63) == 0) { wvs[t >> 6] = bv; wss[t >> 6] = bs; }
        __syncthreads();
        if (t == 0) {
#pragma unroll
            for (int w = 1; w < 4; ++w)
                if (wvs[w] > bv || (wvs[w] == bv && wss[w] < bs)) { bv = wvs[w]; bs = wss[w]; }
            cv[ob + r] = bv;
            ci[ob + r] = base + bs;
            lv[bs] = -1.0e300;
        }
        __syncthreads();
    }
}

// ---------------- top-50 phase B: top-50 of CPB*50 candidates per graph ----------------
__global__ __launch_bounds__(256) void topkB_kernel(const double* __restrict__ cv,
                                                    const int* __restrict__ ci,
                                                    int* __restrict__ topk) {
    const int g = blockIdx.x, t = threadIdx.x;
    const int M = CPB * 50;   // 3200
    __shared__ double lv[CPB * 50];
    __shared__ int li[CPB * 50];
    __shared__ double wvs[4];
    __shared__ int wis[4], wss[4];
    for (int i = t; i < M; i += 256) {
        lv[i] = cv[(size_t)g * M + i];
        li[i] = ci[(size_t)g * M + i];
    }
    __syncthreads();
    for (int r = 0; r < 50; ++r) {
        double bv = -1.0e300; int bi = 0x3fffffff, bs = 0;
        for (int i = t; i < M; i += 256) {
            double v = lv[i]; int idx = li[i];
            if (v > bv || (v == bv && idx < bi)) { bv = v; bi = idx; bs = i; }
        }
#pragma unroll
        for (int off = 32; off; off >>= 1) {
            double ov = __shfl_xor(bv, off);
            int oi = __shfl_xor(bi, off);
            int os = __shfl_xor(bs, off);
            if (ov > bv || (ov == bv && oi < bi)) { bv = ov; bi = oi; bs = os; }
        }
        if ((t & 63) == 0) { wvs[t >> 6] = bv; wis[t >> 6] = bi; wss[t >> 6] = bs; }
        __syncthreads();
        if (t == 0) {
#pragma unroll
            for (int w = 1; w < 4; ++w)
                if (wvs[w] > bv || (wvs[w] == bv && wis[w] < bi)) {
                    bv = wvs[w]; bi = wis[w]; bs = wss[w];
                }
            topk[g * 50 + r] = bi;
            lv[bs] = -1.0e300;
        }
        __syncthreads();
    }
}

// ---------------- pooled rows: d(out1[sel], out2[j]) for 400 rows x 199 cols -----------
__global__ __launch_bounds__(256) void pooled_kernel(const float* __restrict__ out1,
                                                     const float* __restrict__ out2,
                                                     const int* __restrict__ topk,
                                                     float* __restrict__ pooled, int npg) {
    const int bk = blockIdx.x;           // 0..399
    const int g = bk / 50, kk = bk % 50;
    __shared__ float arow[64];
    const int t = threadIdx.x;
    const int node = g * npg + topk[g * 50 + kk];
    if (t < 64) arow[t] = out1[(size_t)node * 64 + t];
    __syncthreads();
    if (t < 199) {
        double na = 0.0, nb = 0.0, dd = 0.0;
        for (int k2 = 0; k2 < 64; ++k2) {
            double a = arow[k2];
            double b = out2[t * 64 + k2];
            na += a * a; nb += b * b; dd += a * b;
        }
        double sq = na + nb - 2.0 * dd;
        pooled[(size_t)g * 9950 + kk * 199 + t] = (float)((sq > 0.0) ? sqrt(sq) : 0.0);
    }
}

// ---------------- fc1 k-split: part[b,ks,f] = sum over chunk ks of p[i]*W[i,f] --------
__global__ __launch_bounds__(256) void fc1_partial_kernel(const float* __restrict__ pooled,
                                                          const float* __restrict__ W,
                                                          double* __restrict__ part) {
    const int b = blockIdx.x >> 6;        // / FKS
    const int ks = blockIdx.x & (FKS - 1);
    const int t = threadIdx.x;
    const int f = t & 127, half = t >> 7;
    const int C = (9950 + FKS - 1) / FKS; // 156
    const int i0 = ks * C;
    const int i1 = (i0 + C < 9950) ? (i0 + C) : 9950;
    const float* p = pooled + (size_t)b * 9950;
    double acc = 0.0;
    for (int i = i0 + half; i < i1; i += 2)
        acc += (double)p[i] * (double)W[(size_t)i * 128 + f];
    __shared__ double red[256];
    red[t] = acc; __syncthreads();
    if (half == 0)
        part[((size_t)b * FKS + ks) * 128 + f] = red[f] + red[128 + f];
}

__global__ __launch_bounds__(128) void fc1_reduce_kernel(const double* __restrict__ part,
                                                         const float* __restrict__ bias,
                                                         float* __restrict__ z1) {
    const int b = blockIdx.x, f = threadIdx.x;
    double acc = 0.0;
    for (int ks = 0; ks < FKS; ++ks)
        acc += part[((size_t)b * FKS + ks) * 128 + f];
    z1[b * 128 + f] = (float)(acc + (double)bias[f]);
}

// ---------------- head: LN+ReLU, fc2, LN+ReLU, fc3, sigmoid ---------------------------
__global__ __launch_bounds__(128) void head_kernel(const float* __restrict__ z1,
                                                   const float* __restrict__ g1,
                                                   const float* __restrict__ be1,
                                                   const float* __restrict__ W2,
                                                   const float* __restrict__ b2,
                                                   const float* __restrict__ g2,
                                                   const float* __restrict__ be2,
                                                   const float* __restrict__ W3,
                                                   const float* __restrict__ b3,
                                                   float* __restrict__ out) {
    const int b = blockIdx.x, t = threadIdx.x;
    __shared__ double red[128];
    __shared__ float shy[128];
    __shared__ float sh2[64];
    float z = z1[b * 128 + t];
    red[t] = z; __syncthreads();
    for (int off = 64; off; off >>= 1) { if (t < off) red[t] += red[t + off]; __syncthreads(); }
    double mu = red[0] / 128.0; __syncthreads();
    double dv = (double)z - mu;
    red[t] = dv * dv; __syncthreads();
    for (int off = 64; off; off >>= 1) { if (t < off) red[t] += red[t + off]; __syncthreads(); }
    double var = red[0] / 128.0; __syncthreads();
    float y = (float)(dv / sqrt(var + 1e-5)) * g1[t] + be1[t];
    shy[t] = fmaxf(y, 0.f); __syncthreads();
    double a2 = 0.0;
    if (t < 64) {
        for (int i = 0; i < 128; ++i) a2 += (double)shy[i] * (double)W2[i * 64 + t];
        a2 += (double)b2[t];
    }
    red[t] = (t < 64) ? a2 : 0.0; __syncthreads();
    for (int off = 64; off; off >>= 1) { if (t < off) red[t] += red[t + off]; __syncthreads(); }
    double mu2 = red[0] / 64.0; __syncthreads();
    double dv2 = a2 - mu2;
    red[t] = (t < 64) ? dv2 * dv2 : 0.0; __syncthreads();
    for (int off = 64; off; off >>= 1) { if (t < off) red[t] += red[t + off]; __syncthreads(); }
    double var2 = red[0] / 64.0; __syncthreads();
    if (t < 64) {
        float h2 = (float)(dv2 / sqrt(var2 + 1e-5)) * g2[t] + be2[t];
        sh2[t] = fmaxf(h2, 0.f);
    }
    __syncthreads();
    red[t] = (t < 64) ? (double)sh2[t] * (double)W3[t] : 0.0; __syncthreads();
    for (int off = 64; off; off >>= 1) { if (t < off) red[t] += red[t + off]; __syncthreads(); }
    if (t == 0) {
        double zf = red[0] + (double)b3[0];
        out[b] = (float)(1.0 / (1.0 + exp(-zf)));
    }
}

// ---------------------------------------------------------------------------
extern "C" void kernel_launch(void* const* d_in, const int* in_sizes, int n_in,
                              void* d_out, int out_size, void* d_ws, size_t ws_size,
                              hipStream_t stream) {
    (void)n_in; (void)out_size; (void)ws_size;
    const float* x1  = (const float*)d_in[0];
    const int*   ei1 = (const int*)d_in[1];
    const float* x2  = (const float*)d_in[3];
    const int*   ei2 = (const int*)d_in[4];
    const float* W1a = (const float*)d_in[5];
    const float* b1a = (const float*)d_in[6];
    const float* W1b = (const float*)d_in[7];
    const float* b1b = (const float*)d_in[8];
    const float* W2a = (const float*)d_in[9];
    const float* b2a = (const float*)d_in[10];
    const float* W2b = (const float*)d_in[11];
    const float* b2b = (const float*)d_in[12];
    const float* f1W = (const float*)d_in[13];
    const float* f1b = (const float*)d_in[14];
    const float* g1  = (const float*)d_in[15];
    const float* be1 = (const float*)d_in[16];
    const float* f2W = (const float*)d_in[17];
    const float* f2b = (const float*)d_in[18];
    const float* g2  = (const float*)d_in[19];
    const float* be2 = (const float*)d_in[20];
    const float* f3W = (const float*)d_in[21];
    const float* f3b = (const float*)d_in[22];
    float* out = (float*)d_out;

    const int n1 = in_sizes[0] / 128;     // 200000
    const int e1 = in_sizes[1] / 2;       // 2000000
    const int n2 = in_sizes[3] / 128;     // 199
    const int e2 = in_sizes[4] / 2;       // 3184
    const int npg = n1 / 8;               // 25000

    // workspace carve-up
    char* p = (char*)d_ws;
    auto alloc = [&](size_t bytes) { char* r = p; p += (bytes + 255) & ~(size_t)255; return r; };
    float*  A    = (float*)alloc((size_t)n1 * 128 * 4);
    float*  Bb   = (float*)alloc((size_t)n1 * 128 * 4);
    double* sc   = (double*)alloc((size_t)n1 * 8);
    int*    rs1  = (int*)alloc((size_t)(n1 + 1) * 4);   // counts -> row_start (in place)
    int*    cur1 = (int*)alloc((size_t)(n1 + 1) * 4);
    int*    csr1 = (int*)alloc((size_t)e1 * 4);
    int*    bsum = (int*)alloc(4096);
    int*    rs2  = (int*)alloc((size_t)(n2 + 1) * 4);
    int*    cur2 = (int*)alloc((size_t)(n2 + 1) * 4);
    int*    csr2 = (int*)alloc((size_t)e2 * 4);
    float*  G2A  = (float*)alloc((size_t)n2 * 128 * 4);
    float*  G2B  = (float*)alloc((size_t)n2 * 128 * 4);
    float*  o2   = (float*)alloc((size_t)n2 * 64 * 4);
    double* cndv = (double*)alloc((size_t)8 * CPB * 50 * 8);
    int*    cndi = (int*)alloc((size_t)8 * CPB * 50 * 4);
    int*    tk   = (int*)alloc(8 * 50 * 4);
    float*  pld  = (float*)alloc((size_t)8 * 9950 * 4);
    double* f1p  = (double*)alloc((size_t)8 * FKS * 128 * 8);
    float*  z1   = (float*)alloc(8 * 128 * 4);

    const int* src1 = ei1;           const int* dst1 = ei1 + e1;
    const int* src2 = ei2;           const int* dst2 = ei2 + e2;

    // ---- CSR build (graph1 then graph2; bsum reused, stream-ordered) ----
    hipMemsetAsync(rs1, 0, (size_t)(n1 + 1) * 4, stream);
    hipMemsetAsync(rs2, 0, (size_t)(n2 + 1) * 4, stream);
    hist_kernel<<<(e1 + 255) / 256, 256, 0, stream>>>(dst1, e1, rs1);
    hist_kernel<<<(e2 + 255) / 256, 256, 0, stream>>>(dst2, e2, rs2);
    int tot1 = n1 + 1, nch1 = (tot1 + 1023) / 1024;
    chunksum_kernel<<<nch1, 256, 0, stream>>>(rs1, tot1, bsum);
    scanchunk_kernel<<<1, 256, 0, stream>>>(bsum, nch1, nullptr, bsum, nullptr);
    scanchunk_kernel<<<nch1, 256, 0, stream>>>(rs1, tot1, bsum, rs1, cur1);
    fill_kernel<<<(e1 + 255) / 256, 256, 0, stream>>>(src1, dst1, e1, cur1, csr1);
    int tot2 = n2 + 1, nch2 = (tot2 + 1023) / 1024;
    chunksum_kernel<<<nch2, 256, 0, stream>>>(rs2, tot2, bsum);
    scanchunk_kernel<<<1, 256, 0, stream>>>(bsum, nch2, nullptr, bsum, nullptr);
    scanchunk_kernel<<<nch2, 256, 0, stream>>>(rs2, tot2, bsum, rs2, cur2);
    fill_kernel<<<(e2 + 255) / 256, 256, 0, stream>>>(src2, dst2, e2, cur2, csr2);

    // ---- GIN graph1 ----
    int gb1 = (n1 + 63) / 64;
    gemm_kernel<128, 128, false, false><<<gb1, 256, 0, stream>>>(x1, W1a, nullptr, A, n1);
    agg_kernel<32><<<(n1 + 7) / 8, 256, 0, stream>>>(A, rs1, csr1, b1a, Bb, n1);
    gemm_kernel<128, 128, true, true><<<gb1, 256, 0, stream>>>(Bb, W1b, b1b, A, n1);
    gemm_kernel<128, 64, false, false><<<gb1, 256, 0, stream>>>(A, W2a, nullptr, Bb, n1);
    agg_kernel<16><<<(n1 + 15) / 16, 256, 0, stream>>>(Bb, rs1, csr1, b2a, A, n1);
    gemm_kernel<64, 64, true, true><<<gb1, 256, 0, stream>>>(A, W2b, b2b, Bb, n1);  // out1 = Bb

    // ---- GIN graph2 ----
    int gb2 = (n2 + 63) / 64;
    gemm_kernel<128, 128, false, false><<<gb2, 256, 0, stream>>>(x2, W1a, nullptr, G2A, n2);
    agg_kernel<32><<<(n2 + 7) / 8, 256, 0, stream>>>(G2A, rs2, csr2, b1a, G2B, n2);
    gemm_kernel<128, 128, true, true><<<gb2, 256, 0, stream>>>(G2B, W1b, b1b, G2A, n2);
    gemm_kernel<128, 64, false, false><<<gb2, 256, 0, stream>>>(G2A, W2a, nullptr, G2B, n2);
    agg_kernel<16><<<(n2 + 15) / 16, 256, 0, stream>>>(G2B, rs2, csr2, b2a, G2A, n2);
    gemm_kernel<64, 64, true, true><<<gb2, 256, 0, stream>>>(G2A, W2b, b2b, o2, n2);   // out2

    // ---- scores -> two-phase top-50 per graph -> pooled rows ----
    scores_kernel<<<(n1 + 3) / 4, 256, 0, stream>>>(Bb, o2, sc, n1);
    topkA_kernel<<<8 * CPB, 256, 0, stream>>>(sc, cndv, cndi, npg);
    topkB_kernel<<<8, 256, 0, stream>>>(cndv, cndi, tk);
    pooled_kernel<<<400, 256, 0, stream>>>(Bb, o2, tk, pld, npg);

    // ---- head ----
    fc1_partial_kernel<<<8 * FKS, 256, 0, stream>>>(pld, f1W, f1p);
    fc1_reduce_kernel<<<8, 128, 0, stream>>>(f1p, f1b, z1);
    head_kernel<<<8, 128, 0, stream>>>(z1, g1, be1, f2W, f2b, g2, be2, f3W, f3b, out);
}